// Round 1
// baseline (270.948 us; speedup 1.0000x reference)
//
#include <hip/hip_runtime.h>

// EdgeVar R9: R8 structure with the main loop re-quantized for load balance.
// Post-mortems R2-R8 established:
//   - The wall is L2 random-request rate: 2E = 25.6M lane-gathers. Request-count
//     bound: record size (4B/8B) and ILP depth don't matter.
//   - Divergent LDS hist atomics + boundary search ride ~free on the LDS pipe.
//   - Separate passes (R7: +30us) and bucket-sorting (R3/R6: +100us) lose.
// R9 theory: the 4-edge/thread/iter grouping gives only 6.1 iters/thread
// (3.2M groups / 524288 threads) -> blocks 0-105 run a 7th iteration while
// 918 blocks idle at the flush barrier (~7-12% of fused time; Occupancy=65%).
// Re-quantize to 1 edge/thread/iter: 24.41 iters/thread -> 24-vs-25 skew is
// ~2.4%. Gather count unchanged (request-bound), streams stay coalesced.

typedef unsigned int u32;

#define GBINS 1024

__device__ __forceinline__ int find_graph(int v, const int* __restrict__ ss, float scale) {
    int g = (int)((float)v * scale);       // ~floor(v*G/N); off by a few
    g = min(g, GBINS - 1);
    while (v < ss[g]) --g;                 // ss[0]=0 guards bottom
    while (v >= ss[g + 1]) ++g;            // ss[GBINS]=N guards top
    return g;
}

// startg[1025] from sorted batch_ids; also zeros gsum/gcnt (replaces memset).
__global__ void prep(const int* __restrict__ batch, int* __restrict__ startg,
                     float* __restrict__ gsum, u32* __restrict__ gcnt, int N) {
    const int i = blockIdx.x * blockDim.x + threadIdx.x;
    if (i < GBINS) { gsum[i] = 0.f; gcnt[i] = 0u; }
    if (i >= N) return;
    const int b = batch[i];
    if (i == 0) { for (int g = 0; g <= b; ++g) startg[g] = 0; }
    else { const int a = batch[i - 1]; for (int g = a + 1; g <= b; ++g) startg[g] = i; }
    if (i == N - 1) { for (int g = b + 1; g <= GBINS; ++g) startg[g] = N; }
}

__global__ __launch_bounds__(512)
void fused_kernel(const int* __restrict__ src, const int* __restrict__ dst,
                  const float2* __restrict__ pos, const int* __restrict__ startg,
                  float* __restrict__ gsum, u32* __restrict__ gcnt,
                  int E, float scale) {
    __shared__ int ss[GBINS + 1];
    __shared__ float hs[GBINS];
    __shared__ u32 hc[GBINS];
    const int tid = threadIdx.x;
    for (int i = tid; i < GBINS + 1; i += 512) ss[i] = startg[i];
    for (int i = tid; i < GBINS; i += 512) { hs[i] = 0.f; hc[i] = 0u; }
    __syncthreads();

    const int gtid = blockIdx.x * 512 + tid, gstride = gridDim.x * 512;

    // 1 edge/thread/iter: work quantum = 64 edges/wave-iter. 12.8M edges /
    // 524288 threads = 24.41 iters -> 24-vs-25 imbalance ~2.4% (was ~12.7%
    // at 4-edge quanta). Gathers per edge unchanged; streams stay coalesced.
    for (int e = gtid; e < E; e += gstride) {
        const int s = __builtin_nontemporal_load(&src[e]);
        const int d = __builtin_nontemporal_load(&dst[e]);
        const float2 a = pos[s];
        const float2 b = pos[d];
        const float dx = b.x - a.x, dy = b.y - a.y;
        const float t  = sqrtf(fmaf(dx, dx, dy * dy)) - 1.f;
        const int g = find_graph(s, ss, scale);
        atomicAdd(&hs[g], t * t);          // LDS pipe: ~free under the L2 wall
        atomicAdd(&hc[g], 1u);
    }

    __syncthreads();
    // striped flush: rotate bin order per block to spread same-address bursts
    for (int j = tid; j < GBINS; j += 512) {
        const int g = (j + (blockIdx.x << 3)) & (GBINS - 1);
        const u32 c = hc[g];
        if (c) { atomicAdd(&gcnt[g], c); atomicAdd(&gsum[g], hs[g]); }
    }
}

__global__ void finalize_kernel(const float* __restrict__ gsum,
                                const u32* __restrict__ gcnt,
                                float* __restrict__ out,
                                const int* __restrict__ nG_ptr) {
    const int G = *nG_ptr;
    float v = 0.f;
    for (int g = threadIdx.x; g < G; g += blockDim.x)
        v += gsum[g] / fmaxf((float)gcnt[g], 1.f);
    __shared__ float w[16];
    for (int off = 32; off; off >>= 1) v += __shfl_down(v, off, 64);
    if ((threadIdx.x & 63) == 0) w[threadIdx.x >> 6] = v;
    __syncthreads();
    if (threadIdx.x == 0) {
        float s = 0.f;
        const int nw = (blockDim.x + 63) >> 6;
        for (int i = 0; i < nw; ++i) s += w[i];
        out[0] = s / (float)G;             // direct store: no d_out memset needed
    }
}

extern "C" void kernel_launch(void* const* d_in, const int* in_sizes, int n_in,
                              void* d_out, int out_size, void* d_ws, size_t ws_size,
                              hipStream_t stream) {
    const float2* pos   = (const float2*)d_in[0];
    const int*    ei    = (const int*)d_in[1];
    const int*    batch = (const int*)d_in[2];
    const int*    nG    = (const int*)d_in[3];

    const int N = in_sizes[0] / 2;
    const int E = in_sizes[1] / 2;
    const int* src = ei;
    const int* dst = ei + E;

    // ws: [gsum 4K][gcnt 4K][startg 1025 ints]
    float* gsum   = (float*)d_ws;
    u32*   gcnt   = (u32*)((char*)d_ws + 4096);
    int*   startg = (int*)((char*)d_ws + 8192);

    const float scale = (float)GBINS / (float)N;
    prep<<<(N + 255) / 256, 256, 0, stream>>>(batch, startg, gsum, gcnt, N);
    fused_kernel<<<1024, 512, 0, stream>>>(src, dst, pos, startg, gsum, gcnt, E, scale);
    finalize_kernel<<<1, 1024, 0, stream>>>(gsum, gcnt, (float*)d_out, nG);
}